// Round 5
// baseline (1415.337 us; speedup 1.0000x reference)
//
#include <hip/hip_runtime.h>

#define NN 10000
#define NE 160000
#define FIN 1152
#define FOUT 288
#define FOUT_TOTAL 1152
#define NF (NN * FOUT)          /* 2,880,000 elems per N x 288 panel */
#define WSL (FIN * FOUT)        /* 331,776 elems per (conv,k) weight slice */
#define NSLICE 22
#define NGRAN 72                /* 288 = 72 granules x 4 features */

typedef __attribute__((ext_vector_type(8))) short short8;
typedef __attribute__((ext_vector_type(4))) unsigned short ushort4v;
typedef __attribute__((ext_vector_type(4))) float floatx4;

__device__ __forceinline__ unsigned short f2bf(float f) {
  unsigned int u = __float_as_uint(f);
  u += 0x7FFF + ((u >> 16) & 1); // round-to-nearest-even
  return (unsigned short)(u >> 16);
}
__device__ __forceinline__ float bf2f(unsigned short u) {
  return __uint_as_float(((unsigned int)u) << 16);
}

// async global->LDS, 16B per lane. LDS dest MUST be wave-uniform base + lane*16.
__device__ __forceinline__ void async_copy16(void* lds, const void* gmem) {
  __builtin_amdgcn_global_load_lds(
      (const __attribute__((address_space(1))) unsigned int*)gmem,
      (__attribute__((address_space(3))) unsigned int*)lds, 16, 0, 0);
}

// ---------------- degree / normalization ----------------

__global__ void deg_kernel(const int* __restrict__ ei, int* __restrict__ deg,
                           int* __restrict__ indeg) {
  int e = blockIdx.x * 256 + threadIdx.x;
  if (e < NE) {
    atomicAdd(&deg[ei[e]], 1);        // out-degree by source (row)
    atomicAdd(&indeg[ei[NE + e]], 1); // in-degree by target (col)
  }
}

__global__ void dinv_kernel(const int* __restrict__ deg, float* __restrict__ dinv) {
  int i = blockIdx.x * 256 + threadIdx.x;
  if (i < NN) {
    int d = deg[i];
    dinv[i] = d > 0 ? rsqrtf((float)d) : 0.0f;
  }
}

// single-block exclusive scan of indeg -> rowptr (and cursor copy)
__global__ void scan_kernel(const int* __restrict__ indeg, int* __restrict__ rowptr,
                            int* __restrict__ cursor) {
  __shared__ int s[256];
  __shared__ int carry_s;
  if (threadIdx.x == 0) carry_s = 0;
  __syncthreads();
  for (int base = 0; base < NN; base += 256) {
    int i = base + threadIdx.x;
    int v = (i < NN) ? indeg[i] : 0;
    s[threadIdx.x] = v;
    __syncthreads();
    for (int off = 1; off < 256; off <<= 1) {
      int t = (threadIdx.x >= off) ? s[threadIdx.x - off] : 0;
      __syncthreads();
      s[threadIdx.x] += t;
      __syncthreads();
    }
    int excl = s[threadIdx.x] - v + carry_s;
    if (i < NN) { rowptr[i] = excl; cursor[i] = excl; }
    __syncthreads();
    if (threadIdx.x == 0) carry_s += s[255];
    __syncthreads();
  }
  if (threadIdx.x == 0) rowptr[NN] = carry_s;
}

__global__ void scatter_kernel(const int* __restrict__ ei, const float* __restrict__ dinv,
                               int* __restrict__ cursor, int* __restrict__ srcarr,
                               float* __restrict__ wn) {
  int e = blockIdx.x * 256 + threadIdx.x;
  if (e < NE) {
    int r = ei[e], c = ei[NE + e];
    int pos = atomicAdd(&cursor[c], 1);
    srcarr[pos] = r;
    wn[pos] = -(dinv[r] * dinv[c]);
  }
}

// ---------------- weight transpose+cast: Wt[slice][o][f] bf16 ----------------
__global__ void wtrans_kernel(const float* __restrict__ W0, const float* __restrict__ W1,
                              const float* __restrict__ W2, const float* __restrict__ W3,
                              unsigned short* __restrict__ Wt) {
  int i = blockIdx.x * 256 + threadIdx.x;
  if (i >= NSLICE * WSL) return;
  int s = i / WSL;
  int rem = i - s * WSL;
  int o = rem / FIN;
  int f = rem - o * FIN;
  int c, k;
  if (s < 4)       { c = 0; k = s; }
  else if (s < 9)  { c = 1; k = s - 4; }
  else if (s < 15) { c = 2; k = s - 9; }
  else             { c = 3; k = s - 15; }
  const float* W = (c == 0) ? W0 : (c == 1) ? W1 : (c == 2) ? W2 : W3;
  Wt[i] = f2bf(W[(size_t)k * WSL + (size_t)f * FOUT + o]);
}

// ---------------- x -> bf16 cast ----------------
__global__ void xcast_kernel(const float* __restrict__ x, unsigned short* __restrict__ xb) {
  int i = blockIdx.x * 256 + threadIdx.x; // one float4 group per thread
  if (i < NN * FIN / 4) {
    float4 v = *(const float4*)(x + (size_t)i * 4);
    ushort4 r;
    r.x = f2bf(v.x); r.y = f2bf(v.y); r.z = f2bf(v.z); r.w = f2bf(v.w);
    *(ushort4*)(xb + (size_t)i * 4) = r;
  }
}

// ---------------- MFMA GEMM: Y[slice] = bf16( xb @ Wt[slice]^T ) ----------------
// Block tile 128x96, K=1152 (BK=64), 4 waves in 2x2, wave tile 64x48 = 4x3 mfma frags.
// Grid: x = (slice, ntile) [66], y = mtile [79].
// LDS XOR-swizzle (T2, rule 21) verified R2: SQ_LDS_BANK_CONFLICT 6.3e7 -> 0,
// 235 -> 187.7 us. UNCHANGED since.
__global__ __launch_bounds__(256) void gemm_mfma_kernel(
    const unsigned short* __restrict__ Xb, const unsigned short* __restrict__ Wt,
    unsigned short* __restrict__ Yall) {
  const int bx = blockIdx.x;
  const int slice = bx / 3;
  const int n0 = (bx - slice * 3) * 96;
  const int m0 = blockIdx.y * 128;

  __shared__ unsigned short As[128][64]; // [m][k] rows of 128 B (chunk-swizzled)
  __shared__ unsigned short Bs[96][64];  // [o][f] (chunk-swizzled)

  const int tid = threadIdx.x;
  const int lane = tid & 63;
  const int wave = tid >> 6;
  const int wx = wave & 1;        // n-dir
  const int wy = wave >> 1;       // m-dir
  const int lm = lane & 15;
  const int hi = lane >> 4;       // 16B chunk sub-index within 64B k-phase

  floatx4 acc[4][3];
#pragma unroll
  for (int i = 0; i < 4; i++)
#pragma unroll
    for (int j = 0; j < 3; j++) acc[i][j] = (floatx4){0.f, 0.f, 0.f, 0.f};

  const unsigned short* Wbase = Wt + (size_t)slice * WSL;

  for (int f0 = 0; f0 < FIN; f0 += 64) {
    __syncthreads(); // protect LDS from previous iteration's readers
    // stage A: 128 rows x 128 B, lane-linear LDS dest, swizzled global source
#pragma unroll
    for (int i = 0; i < 4; i++) {
      int idx = i * 256 + tid;
      int row = idx >> 3;
      int ck = idx & 7;
      int gr = m0 + row;
      gr = gr < NN ? gr : NN - 1; // clamp (masked at store)
      async_copy16((char*)&As[0][0] + idx * 16,
                   (const char*)Xb + ((size_t)gr * FIN + f0) * 2 + ((ck ^ (row & 7)) << 4));
    }
    // stage B: 96 rows x 128 B
#pragma unroll
    for (int i = 0; i < 3; i++) {
      int idx = i * 256 + tid;
      int row = idx >> 3;
      int ck = idx & 7;
      async_copy16((char*)&Bs[0][0] + idx * 16,
                   (const char*)Wbase + ((size_t)(n0 + row) * FIN + f0) * 2 + ((ck ^ (row & 7)) << 4));
    }
    __syncthreads();
#pragma unroll
    for (int s = 0; s < 2; s++) {
      short8 a[4], b[3];
#pragma unroll
      for (int i = 0; i < 4; i++) {
        int ar = wy * 64 + i * 16 + lm;
        a[i] = *(const short8*)((const char*)&As[ar][0] + (((s * 4 + hi) ^ (ar & 7)) << 4));
      }
#pragma unroll
      for (int j = 0; j < 3; j++) {
        int br = wx * 48 + j * 16 + lm;
        b[j] = *(const short8*)((const char*)&Bs[br][0] + (((s * 4 + hi) ^ (br & 7)) << 4));
      }
#pragma unroll
      for (int i = 0; i < 4; i++)
#pragma unroll
        for (int j = 0; j < 3; j++)
          acc[i][j] = __builtin_amdgcn_mfma_f32_16x16x32_bf16(a[i], b[j], acc[i][j], 0, 0, 0);
    }
  }
  // epilogue: C/D layout col=lane&15, row=(lane>>4)*4+reg -> bf16 Y panel
  unsigned short* Yb = Yall + (size_t)slice * NF;
  const int cbase = n0 + wx * 48 + lm;
  const int rbase = (lane >> 4) * 4;
#pragma unroll
  for (int i = 0; i < 4; i++) {
#pragma unroll
    for (int r = 0; r < 4; r++) {
      int grow = m0 + wy * 64 + i * 16 + rbase + r;
      if (grow < NN) {
        unsigned short* op = Yb + (size_t)grow * FOUT + cbase;
#pragma unroll
        for (int j = 0; j < 3; j++) op[j * 16] = f2bf(acc[i][j][r]);
      }
    }
  }
}

// ---------------- Clenshaw steps: LDS-resident column-slice gather --------------
// b_k = Y_k + 2*L*b_{k+1} - b_{k+2}   (N x 288 bf16 panels; fp32 accumulate)
// R2-R4 evidence: per-thread MLP (+36us), blockIdx XCD jobs (0), physical-XCD
// work queues (-300us) all failed -> the cost is the per-edge random global
// transaction itself, not cache capacity or ILP. Fix: serve gathers from LDS.
// Block = (slot, granule of 4 features): stage the ENTIRE column slice
// H[:, g*4 .. g*4+4) = 10000 x 8 B = 80,000 B into LDS (coalesced stream,
// 2 blocks/CU), then each edge gather is a ds_read_b64 (69 TB/s aggregate)
// instead of a random 16 B global read. Chip LDS gather traffic: 18 x 92 MB
// = 1.66 GB -> ~25 us floor. Edge accumulation order (ascending p, u) is
// identical to the verified R2/R3 kernels.

struct StepB {
  const unsigned short* H[4]; // gather source  b_{k+1}  (per slot)
  const unsigned short* Y[4]; // additive Y_k
  const unsigned short* P[4]; // b_{k+2} (may be null; block-uniform branch)
  unsigned short* D[4];       // dest b_k
};

__global__ __launch_bounds__(576) void cl_step_lds(
    StepB a, const int* __restrict__ rowptr, const int* __restrict__ srcarr,
    const float* __restrict__ wn) {
  __shared__ unsigned short Hs[NN * 4]; // 80,000 B column slice
  const int slot = blockIdx.x / NGRAN;
  const int g = blockIdx.x - slot * NGRAN;
  const int off = g * 4;
  const unsigned short* __restrict__ H = a.H[slot];
  const int t = threadIdx.x;

  for (int i = t; i < NN; i += 576)
    *(ushort4v*)&Hs[i * 4] = *(const ushort4v*)(H + (size_t)i * FOUT + off);
  __syncthreads();

  const unsigned short* __restrict__ Yp = a.Y[slot];
  const unsigned short* __restrict__ Pp = a.P[slot];
  unsigned short* __restrict__ Dp = a.D[slot];

  for (int node = t; node < NN; node += 576) {
    const int rs = rowptr[node];
    const int re = rowptr[node + 1];
    float acc[4] = {0.f, 0.f, 0.f, 0.f};
    int p = rs;
    for (; p + 4 <= re; p += 4) {
      int r[4];
      float w[4];
#pragma unroll
      for (int u = 0; u < 4; u++) { r[u] = srcarr[p + u]; w[u] = wn[p + u]; }
      ushort4v h[4];
#pragma unroll
      for (int u = 0; u < 4; u++) h[u] = *(const ushort4v*)&Hs[r[u] * 4];
#pragma unroll
      for (int u = 0; u < 4; u++)
#pragma unroll
        for (int q = 0; q < 4; q++) acc[q] += w[u] * bf2f(h[u][q]);
    }
    for (; p < re; ++p) {
      int r = srcarr[p];
      float w = wn[p];
      ushort4v h = *(const ushort4v*)&Hs[r * 4];
#pragma unroll
      for (int q = 0; q < 4; q++) acc[q] += w * bf2f(h[q]);
    }
    size_t o = (size_t)node * FOUT + off;
    ushort4v y = *(const ushort4v*)(Yp + o);
    ushort4v d;
    if (Pp) {
      ushort4v pp = *(const ushort4v*)(Pp + o);
#pragma unroll
      for (int q = 0; q < 4; q++) d[q] = f2bf(bf2f(y[q]) + 2.f * acc[q] - bf2f(pp[q]));
    } else {
#pragma unroll
      for (int q = 0; q < 4; q++) d[q] = f2bf(bf2f(y[q]) + 2.f * acc[q]);
    }
    *(ushort4v*)(Dp + o) = d;
  }
}

// final: out[:, c*288 + f] = bias[f] + Y_0 + L*b_1 - b_2 (fp32 out)
struct FinalB {
  const unsigned short* H[4]; // b_1
  const unsigned short* Y[4]; // Y_0
  const unsigned short* P[4]; // b_2
  const float* B[4];          // bias
  int conv[4];
};

__global__ __launch_bounds__(576) void cl_final_lds(
    FinalB a, const int* __restrict__ rowptr, const int* __restrict__ srcarr,
    const float* __restrict__ wn, float* __restrict__ out) {
  __shared__ unsigned short Hs[NN * 4]; // 80,000 B column slice
  const int slot = blockIdx.x / NGRAN;
  const int g = blockIdx.x - slot * NGRAN;
  const int off = g * 4;
  const unsigned short* __restrict__ H = a.H[slot];
  const int t = threadIdx.x;

  for (int i = t; i < NN; i += 576)
    *(ushort4v*)&Hs[i * 4] = *(const ushort4v*)(H + (size_t)i * FOUT + off);
  __syncthreads();

  const unsigned short* __restrict__ Yp = a.Y[slot];
  const unsigned short* __restrict__ Pp = a.P[slot];
  const float* __restrict__ bias = a.B[slot] + off;
  const int conv = a.conv[slot];

  for (int node = t; node < NN; node += 576) {
    const int rs = rowptr[node];
    const int re = rowptr[node + 1];
    float acc[4] = {0.f, 0.f, 0.f, 0.f};
    int p = rs;
    for (; p + 4 <= re; p += 4) {
      int r[4];
      float w[4];
#pragma unroll
      for (int u = 0; u < 4; u++) { r[u] = srcarr[p + u]; w[u] = wn[p + u]; }
      ushort4v h[4];
#pragma unroll
      for (int u = 0; u < 4; u++) h[u] = *(const ushort4v*)&Hs[r[u] * 4];
#pragma unroll
      for (int u = 0; u < 4; u++)
#pragma unroll
        for (int q = 0; q < 4; q++) acc[q] += w[u] * bf2f(h[u][q]);
    }
    for (; p < re; ++p) {
      int r = srcarr[p];
      float w = wn[p];
      ushort4v h = *(const ushort4v*)&Hs[r * 4];
#pragma unroll
      for (int q = 0; q < 4; q++) acc[q] += w * bf2f(h[q]);
    }
    size_t o = (size_t)node * FOUT + off;
    ushort4v y = *(const ushort4v*)(Yp + o);
    ushort4v pp = *(const ushort4v*)(Pp + o);
    float r4[4];
#pragma unroll
    for (int q = 0; q < 4; q++)
      r4[q] = bias[q] + bf2f(y[q]) + acc[q] - bf2f(pp[q]);
    float* op = out + (size_t)node * FOUT_TOTAL + conv * FOUT + off;
    *(float4*)op = make_float4(r4[0], r4[1], r4[2], r4[3]);
  }
}

// ---------------- launch ----------------

extern "C" void kernel_launch(void* const* d_in, const int* in_sizes, int n_in,
                              void* d_out, int out_size, void* d_ws, size_t ws_size,
                              hipStream_t stream) {
  const float* x = (const float*)d_in[0];
  const int* ei = (const int*)d_in[1];
  const float* W[4] = {(const float*)d_in[2], (const float*)d_in[4],
                       (const float*)d_in[6], (const float*)d_in[8]};
  const float* b[4] = {(const float*)d_in[3], (const float*)d_in[5],
                       (const float*)d_in[7], (const float*)d_in[9]};
  float* out = (float*)d_out;

  char* ws = (char*)d_ws;
  size_t off = 0;
  auto alloc = [&](size_t bytes) -> char* {
    char* p = ws + off;
    off += (bytes + 255) & ~(size_t)255;
    return p;
  };
  int* deg = (int*)alloc(NN * 4);
  int* indeg = (int*)alloc(NN * 4);
  int* rowptr = (int*)alloc((NN + 1) * 4);
  int* cursor = (int*)alloc(NN * 4);
  int* srcarr = (int*)alloc(NE * 4);
  float* wn = (float*)alloc(NE * 4);
  float* dinv = (float*)alloc(NN * 4);
  unsigned short* xb = (unsigned short*)alloc((size_t)NN * FIN * 2);       // bf16 x; reused as 4 spare panels
  unsigned short* Wt = (unsigned short*)alloc((size_t)NSLICE * WSL * 2);   // bf16 W^T
  unsigned short* Yall = (unsigned short*)alloc((size_t)NSLICE * NF * 2);  // bf16 Y panels

  hipMemsetAsync(deg, 0, NN * 4, stream);
  hipMemsetAsync(indeg, 0, NN * 4, stream);

  deg_kernel<<<(NE + 255) / 256, 256, 0, stream>>>(ei, deg, indeg);
  dinv_kernel<<<(NN + 255) / 256, 256, 0, stream>>>(deg, dinv);
  scan_kernel<<<1, 256, 0, stream>>>(indeg, rowptr, cursor);
  scatter_kernel<<<(NE + 255) / 256, 256, 0, stream>>>(ei, dinv, cursor, srcarr, wn);
  wtrans_kernel<<<(NSLICE * WSL + 255) / 256, 256, 0, stream>>>(W[0], W[1], W[2], W[3], Wt);
  xcast_kernel<<<(NN * FIN / 4 + 255) / 256, 256, 0, stream>>>(x, xb);

  // all 22 GEMMs in one dispatch; x = (slice,ntile) fastest for A-tile L2 reuse
  {
    dim3 grid(3 * NSLICE, (NN + 127) / 128);
    gemm_mfma_kernel<<<grid, 256, 0, stream>>>(xb, Wt, Yall);
  }

  // ---- Clenshaw schedule (host-side bookkeeping) ----
  const int nK[4] = {4, 5, 6, 7};
  const int st[4] = {0, 4, 9, 15};
  unsigned short* S[4]; // spare panels alias xb (xb no longer needed after GEMM)
  for (int c = 0; c < 4; c++) S[c] = xb + (size_t)c * NF;

  StepB sched[5];
  int nact[5] = {0, 0, 0, 0, 0};
  FinalB fa;

  for (int c = 3; c >= 0; c--) {
    int n = nK[c] - 1;        // Clenshaw degree (props per conv)
    int s0 = 6 - n;           // first global step for this conv
    unsigned short* Yn = Yall + (size_t)(st[c] + n) * NF; // holds b_n = Y_n initially
    unsigned short* A = S[c];
    for (int p = 1; p <= n; p++) {
      int s = s0 + p - 1;
      if (p < n) {
        unsigned short* H = (p & 1) ? Yn : A;
        unsigned short* D = (p & 1) ? A : Yn;
        int j = nact[s]++;
        sched[s].H[j] = H;
        sched[s].Y[j] = Yall + (size_t)(st[c] + n - p) * NF;
        sched[s].P[j] = (p == 1) ? nullptr : D; // in-place over b_{k+2}
        sched[s].D[j] = D;
      } else { // final at s == 5
        int j = 3 - c;
        fa.H[j] = ((n - 1) & 1) ? A : Yn; // loc(b_1)
        fa.P[j] = ((n - 2) & 1) ? A : Yn; // loc(b_2)
        fa.Y[j] = Yall + (size_t)st[c] * NF;
        fa.B[j] = b[c];
        fa.conv[j] = c;
      }
    }
  }

  // pad unused slots with slot 0 (never dereferenced: grid bound = nact*NGRAN)
  for (int s = 0; s < 5; s++)
    for (int j = nact[s]; j < 4; j++) {
      sched[s].H[j] = sched[s].H[0];
      sched[s].Y[j] = sched[s].Y[0];
      sched[s].P[j] = sched[s].P[0];
      sched[s].D[j] = sched[s].D[0];
    }

  for (int s = 0; s < 5; s++)
    cl_step_lds<<<nact[s] * NGRAN, 576, 0, stream>>>(sched[s], rowptr, srcarr, wn);
  cl_final_lds<<<4 * NGRAN, 576, 0, stream>>>(fa, rowptr, srcarr, wn, out);
}

// Round 7
// 728.133 us; speedup vs baseline: 1.9438x; 1.9438x over previous
//
#include <hip/hip_runtime.h>

#define NN 10000
#define NE 160000
#define FIN 1152
#define FOUT 288
#define FOUT_TOTAL 1152
#define NF (NN * FOUT)          /* 2,880,000 elems per N x 288 panel */
#define WSL (FIN * FOUT)        /* 331,776 elems per (conv,k) weight slice */
#define NSLICE 22
#define NMT 79                  /* mtiles */
#define GEMM_BLOCKS 5688        /* 8 XCD lanes x 711 max work per lane */

typedef __attribute__((ext_vector_type(8))) short short8;
typedef __attribute__((ext_vector_type(8))) unsigned short ushort8v;
typedef __attribute__((ext_vector_type(4))) float floatx4;

__device__ __forceinline__ unsigned short f2bf(float f) {
  unsigned int u = __float_as_uint(f);
  u += 0x7FFF + ((u >> 16) & 1); // round-to-nearest-even
  return (unsigned short)(u >> 16);
}
__device__ __forceinline__ float bf2f(unsigned short u) {
  return __uint_as_float(((unsigned int)u) << 16);
}

// async global->LDS, 16B per lane. LDS dest MUST be wave-uniform base + lane*16.
__device__ __forceinline__ void async_copy16(void* lds, const void* gmem) {
  __builtin_amdgcn_global_load_lds(
      (const __attribute__((address_space(1))) unsigned int*)gmem,
      (__attribute__((address_space(3))) unsigned int*)lds, 16, 0, 0);
}

// ---------------- degree / normalization ----------------

__global__ void deg_kernel(const int* __restrict__ ei, int* __restrict__ deg,
                           int* __restrict__ indeg) {
  int e = blockIdx.x * 256 + threadIdx.x;
  if (e < NE) {
    atomicAdd(&deg[ei[e]], 1);        // out-degree by source (row)
    atomicAdd(&indeg[ei[NE + e]], 1); // in-degree by target (col)
  }
}

__global__ void dinv_kernel(const int* __restrict__ deg, float* __restrict__ dinv) {
  int i = blockIdx.x * 256 + threadIdx.x;
  if (i < NN) {
    int d = deg[i];
    dinv[i] = d > 0 ? rsqrtf((float)d) : 0.0f;
  }
}

// single-block exclusive scan of indeg -> rowptr (and cursor copy)
__global__ void scan_kernel(const int* __restrict__ indeg, int* __restrict__ rowptr,
                            int* __restrict__ cursor) {
  __shared__ int s[256];
  __shared__ int carry_s;
  if (threadIdx.x == 0) carry_s = 0;
  __syncthreads();
  for (int base = 0; base < NN; base += 256) {
    int i = base + threadIdx.x;
    int v = (i < NN) ? indeg[i] : 0;
    s[threadIdx.x] = v;
    __syncthreads();
    for (int off = 1; off < 256; off <<= 1) {
      int t = (threadIdx.x >= off) ? s[threadIdx.x - off] : 0;
      __syncthreads();
      s[threadIdx.x] += t;
      __syncthreads();
    }
    int excl = s[threadIdx.x] - v + carry_s;
    if (i < NN) { rowptr[i] = excl; cursor[i] = excl; }
    __syncthreads();
    if (threadIdx.x == 0) carry_s += s[255];
    __syncthreads();
  }
  if (threadIdx.x == 0) rowptr[NN] = carry_s;
}

__global__ void scatter_kernel(const int* __restrict__ ei, const float* __restrict__ dinv,
                               int* __restrict__ cursor, int* __restrict__ srcarr,
                               float* __restrict__ wn) {
  int e = blockIdx.x * 256 + threadIdx.x;
  if (e < NE) {
    int r = ei[e], c = ei[NE + e];
    int pos = atomicAdd(&cursor[c], 1);
    srcarr[pos] = r;
    wn[pos] = -(dinv[r] * dinv[c]);
  }
}

// ---------------- weight transpose+cast: Wt[slice][o][f] bf16 ----------------
__global__ void wtrans_kernel(const float* __restrict__ W0, const float* __restrict__ W1,
                              const float* __restrict__ W2, const float* __restrict__ W3,
                              unsigned short* __restrict__ Wt) {
  int i = blockIdx.x * 256 + threadIdx.x;
  if (i >= NSLICE * WSL) return;
  int s = i / WSL;
  int rem = i - s * WSL;
  int o = rem / FIN;
  int f = rem - o * FIN;
  int c, k;
  if (s < 4)       { c = 0; k = s; }
  else if (s < 9)  { c = 1; k = s - 4; }
  else if (s < 15) { c = 2; k = s - 9; }
  else             { c = 3; k = s - 15; }
  const float* W = (c == 0) ? W0 : (c == 1) ? W1 : (c == 2) ? W2 : W3;
  Wt[i] = f2bf(W[(size_t)k * WSL + (size_t)f * FOUT + o]);
}

// ---------------- x -> bf16 cast ----------------
__global__ void xcast_kernel(const float* __restrict__ x, unsigned short* __restrict__ xb) {
  int i = blockIdx.x * 256 + threadIdx.x; // one float4 group per thread
  if (i < NN * FIN / 4) {
    float4 v = *(const float4*)(x + (size_t)i * 4);
    ushort4 r;
    r.x = f2bf(v.x); r.y = f2bf(v.y); r.z = f2bf(v.z); r.w = f2bf(v.w);
    *(ushort4*)(xb + (size_t)i * 4) = r;
  }
}

// ---------------- MFMA GEMM: Y[slice] = bf16( xb @ Wt[slice]^T ) ----------------
// Block tile 128x96, K=1152 (BK=64), 4 waves in 2x2, wave tile 64x48 = 4x3 frags.
// LDS XOR-swizzle verified R2 (conflicts 6.3e7 -> 0). Inner body UNCHANGED.
// NEW (R7): XCD-ownership block order. Consecutive blockIdx round-robin over
// XCDs (T1 mechanism), so lane j = L&7 pins a slice-set {j, j+8, j+16} to one
// XCD: its ~2 MB of B tiles stay L2-resident for the whole mtile sweep, and per
// mtile the 9 (or 6) co-XCD blocks share one A-row. Expected FETCH_SIZE
// 533 -> ~300 MB. If time doesn't follow, the 35.5% MfmaUtil = m97-structure
// ceiling is confirmed and the next step is the 8-phase rewrite.
// Grid is 1D, split into 3 dispatches (Lofs) so Clenshaw dispatches surface in
// rocprof top-5. Idle blocks (474 of 5688) return uniformly before any barrier.
__global__ __launch_bounds__(256) void gemm_mfma_kernel(
    const unsigned short* __restrict__ Xb, const unsigned short* __restrict__ Wt,
    unsigned short* __restrict__ Yall, int Lofs) {
  const int L = Lofs + blockIdx.x;
  const int j = L & 7;                 // XCD lane (round-robin heuristic)
  const int m = L >> 3;                // work index within XCD lane
  const int nsl = (j < 6) ? 3 : 2;     // slices owned by this lane
  const int work = nsl * 3 * NMT;
  if (m >= work) return;               // uniform early-out, before barriers
  const int mtile = m / (nsl * 3);
  const int rem = m - mtile * (nsl * 3);
  const int slice = j + 8 * (rem / 3); // j<6: {j,j+8,j+16}; j>=6: {j,j+8}
  const int n0 = (rem % 3) * 96;
  const int m0 = mtile * 128;

  __shared__ unsigned short As[128][64]; // [m][k] rows of 128 B (chunk-swizzled)
  __shared__ unsigned short Bs[96][64];  // [o][f] (chunk-swizzled)

  const int tid = threadIdx.x;
  const int lane = tid & 63;
  const int wave = tid >> 6;
  const int wx = wave & 1;        // n-dir
  const int wy = wave >> 1;       // m-dir
  const int lm = lane & 15;
  const int hi = lane >> 4;       // 16B chunk sub-index within 64B k-phase

  floatx4 acc[4][3];
#pragma unroll
  for (int i = 0; i < 4; i++)
#pragma unroll
    for (int jj = 0; jj < 3; jj++) acc[i][jj] = (floatx4){0.f, 0.f, 0.f, 0.f};

  const unsigned short* Wbase = Wt + (size_t)slice * WSL;

  for (int f0 = 0; f0 < FIN; f0 += 64) {
    __syncthreads(); // protect LDS from previous iteration's readers
    // stage A: 128 rows x 128 B, lane-linear LDS dest, swizzled global source
#pragma unroll
    for (int i = 0; i < 4; i++) {
      int idx = i * 256 + tid;
      int row = idx >> 3;
      int ck = idx & 7;
      int gr = m0 + row;
      gr = gr < NN ? gr : NN - 1; // clamp (masked at store)
      async_copy16((char*)&As[0][0] + idx * 16,
                   (const char*)Xb + ((size_t)gr * FIN + f0) * 2 + ((ck ^ (row & 7)) << 4));
    }
    // stage B: 96 rows x 128 B
#pragma unroll
    for (int i = 0; i < 3; i++) {
      int idx = i * 256 + tid;
      int row = idx >> 3;
      int ck = idx & 7;
      async_copy16((char*)&Bs[0][0] + idx * 16,
                   (const char*)Wbase + ((size_t)(n0 + row) * FIN + f0) * 2 + ((ck ^ (row & 7)) << 4));
    }
    __syncthreads();
#pragma unroll
    for (int s = 0; s < 2; s++) {
      short8 a[4], b[3];
#pragma unroll
      for (int i = 0; i < 4; i++) {
        int ar = wy * 64 + i * 16 + lm;
        a[i] = *(const short8*)((const char*)&As[ar][0] + (((s * 4 + hi) ^ (ar & 7)) << 4));
      }
#pragma unroll
      for (int jj = 0; jj < 3; jj++) {
        int br = wx * 48 + jj * 16 + lm;
        b[jj] = *(const short8*)((const char*)&Bs[br][0] + (((s * 4 + hi) ^ (br & 7)) << 4));
      }
#pragma unroll
      for (int i = 0; i < 4; i++)
#pragma unroll
        for (int jj = 0; jj < 3; jj++)
          acc[i][jj] = __builtin_amdgcn_mfma_f32_16x16x32_bf16(a[i], b[jj], acc[i][jj], 0, 0, 0);
    }
  }
  // epilogue: C/D layout col=lane&15, row=(lane>>4)*4+reg -> bf16 Y panel
  unsigned short* Yb = Yall + (size_t)slice * NF;
  const int cbase = n0 + wx * 48 + lm;
  const int rbase = (lane >> 4) * 4;
#pragma unroll
  for (int i = 0; i < 4; i++) {
#pragma unroll
    for (int r = 0; r < 4; r++) {
      int grow = m0 + wy * 64 + i * 16 + rbase + r;
      if (grow < NN) {
        unsigned short* op = Yb + (size_t)grow * FOUT + cbase;
#pragma unroll
        for (int jj = 0; jj < 3; jj++) op[jj * 16] = f2bf(acc[i][jj][r]);
      }
    }
  }
}

// ---------------- Clenshaw steps (slot-FUSED; verified R3 bodies, unchanged) ---
// b_k = Y_k + 2*L*b_{k+1} - b_{k+2}   (all N x 288 bf16 panels; fp32 accumulate)
// Block: 576 threads = 16 nodes x 36 lanes, 16B (8 bf16) per lane.

struct StepA {
  const unsigned short* H[4]; // gather source  b_{k+1}  (per slot)
  const unsigned short* Y[4]; // additive Y_k
  const unsigned short* P[4]; // b_{k+2} (may be null; uniform branch)
  unsigned short* D[4];       // dest b_k
};

template <int NACT>
__global__ __launch_bounds__(576) void cl_step_fused(
    StepA a, const int* __restrict__ rowptr, const int* __restrict__ srcarr,
    const float* __restrict__ wn) {
  const int t = threadIdx.x;
  const int ln = t % 36;
  const int node = blockIdx.x * 16 + t / 36;
  if (node >= NN) return;
  const int off = ln * 8;
  const int rs = rowptr[node];
  const int re = rowptr[node + 1];
  float acc[NACT][8];
#pragma unroll
  for (int s = 0; s < NACT; s++)
#pragma unroll
    for (int q = 0; q < 8; q++) acc[s][q] = 0.f;

  constexpr int U = (NACT <= 2) ? 4 : 2; // edge unroll: keep ~8 loads in flight
  int p = rs;
  for (; p + U <= re; p += U) {
    int r[U];
    float w[U];
#pragma unroll
    for (int u = 0; u < U; u++) { r[u] = srcarr[p + u]; w[u] = wn[p + u]; }
    ushort8v h[U][NACT];
#pragma unroll
    for (int u = 0; u < U; u++)
#pragma unroll
      for (int s = 0; s < NACT; s++)
        h[u][s] = *(const ushort8v*)(a.H[s] + (size_t)r[u] * FOUT + off);
#pragma unroll
    for (int u = 0; u < U; u++)
#pragma unroll
      for (int s = 0; s < NACT; s++)
#pragma unroll
        for (int q = 0; q < 8; q++) acc[s][q] += w[u] * bf2f(h[u][s][q]);
  }
  for (; p < re; ++p) {
    int r = srcarr[p];
    float w = wn[p];
#pragma unroll
    for (int s = 0; s < NACT; s++) {
      ushort8v hh = *(const ushort8v*)(a.H[s] + (size_t)r * FOUT + off);
#pragma unroll
      for (int q = 0; q < 8; q++) acc[s][q] += w * bf2f(hh[q]);
    }
  }

  size_t o = (size_t)node * FOUT + off;
#pragma unroll
  for (int s = 0; s < NACT; s++) {
    ushort8v y = *(const ushort8v*)(a.Y[s] + o);
    ushort8v d;
    if (a.P[s]) {
      ushort8v pp = *(const ushort8v*)(a.P[s] + o);
#pragma unroll
      for (int q = 0; q < 8; q++) d[q] = f2bf(bf2f(y[q]) + 2.f * acc[s][q] - bf2f(pp[q]));
    } else {
#pragma unroll
      for (int q = 0; q < 8; q++) d[q] = f2bf(bf2f(y[q]) + 2.f * acc[s][q]);
    }
    *(ushort8v*)(a.D[s] + o) = d;
  }
}

// final: out[:, c*288 + f] = bias[f] + Y_0 + L*b_1 - b_2 (fp32 out), all 4 convs fused
struct FinalA {
  const unsigned short* H[4]; // b_1
  const unsigned short* Y[4]; // Y_0
  const unsigned short* P[4]; // b_2
  const float* B[4];          // bias
  int conv[4];
};

__global__ __launch_bounds__(576) void cl_final_fused(
    FinalA a, const int* __restrict__ rowptr, const int* __restrict__ srcarr,
    const float* __restrict__ wn, float* __restrict__ out) {
  const int t = threadIdx.x;
  const int ln = t % 36;
  const int node = blockIdx.x * 16 + t / 36;
  if (node >= NN) return;
  const int off = ln * 8;
  const int rs = rowptr[node];
  const int re = rowptr[node + 1];
  float acc[4][8];
#pragma unroll
  for (int s = 0; s < 4; s++)
#pragma unroll
    for (int q = 0; q < 8; q++) acc[s][q] = 0.f;

  constexpr int U = 2;
  int p = rs;
  for (; p + U <= re; p += U) {
    int r[U];
    float w[U];
#pragma unroll
    for (int u = 0; u < U; u++) { r[u] = srcarr[p + u]; w[u] = wn[p + u]; }
    ushort8v h[U][4];
#pragma unroll
    for (int u = 0; u < U; u++)
#pragma unroll
      for (int s = 0; s < 4; s++)
        h[u][s] = *(const ushort8v*)(a.H[s] + (size_t)r[u] * FOUT + off);
#pragma unroll
    for (int u = 0; u < U; u++)
#pragma unroll
      for (int s = 0; s < 4; s++)
#pragma unroll
        for (int q = 0; q < 8; q++) acc[s][q] += w[u] * bf2f(h[u][s][q]);
  }
  for (; p < re; ++p) {
    int r = srcarr[p];
    float w = wn[p];
#pragma unroll
    for (int s = 0; s < 4; s++) {
      ushort8v hh = *(const ushort8v*)(a.H[s] + (size_t)r * FOUT + off);
#pragma unroll
      for (int q = 0; q < 8; q++) acc[s][q] += w * bf2f(hh[q]);
    }
  }

  size_t o = (size_t)node * FOUT + off;
#pragma unroll
  for (int s = 0; s < 4; s++) {
    ushort8v y = *(const ushort8v*)(a.Y[s] + o);
    ushort8v pp = *(const ushort8v*)(a.P[s] + o);
    const float* bias = a.B[s] + off;
    float r8[8];
#pragma unroll
    for (int q = 0; q < 8; q++)
      r8[q] = bias[q] + bf2f(y[q]) + acc[s][q] - bf2f(pp[q]);
    float* op = out + (size_t)node * FOUT_TOTAL + a.conv[s] * FOUT + off;
    *(float4*)(op + 0) = make_float4(r8[0], r8[1], r8[2], r8[3]);
    *(float4*)(op + 4) = make_float4(r8[4], r8[5], r8[6], r8[7]);
  }
}

// ---------------- launch ----------------

extern "C" void kernel_launch(void* const* d_in, const int* in_sizes, int n_in,
                              void* d_out, int out_size, void* d_ws, size_t ws_size,
                              hipStream_t stream) {
  const float* x = (const float*)d_in[0];
  const int* ei = (const int*)d_in[1];
  const float* W[4] = {(const float*)d_in[2], (const float*)d_in[4],
                       (const float*)d_in[6], (const float*)d_in[8]};
  const float* b[4] = {(const float*)d_in[3], (const float*)d_in[5],
                       (const float*)d_in[7], (const float*)d_in[9]};
  float* out = (float*)d_out;

  char* ws = (char*)d_ws;
  size_t off = 0;
  auto alloc = [&](size_t bytes) -> char* {
    char* p = ws + off;
    off += (bytes + 255) & ~(size_t)255;
    return p;
  };
  int* deg = (int*)alloc(NN * 4);
  int* indeg = (int*)alloc(NN * 4);
  int* rowptr = (int*)alloc((NN + 1) * 4);
  int* cursor = (int*)alloc(NN * 4);
  int* srcarr = (int*)alloc(NE * 4);
  float* wn = (float*)alloc(NE * 4);
  float* dinv = (float*)alloc(NN * 4);
  unsigned short* xb = (unsigned short*)alloc((size_t)NN * FIN * 2);       // bf16 x; reused as 4 spare panels
  unsigned short* Wt = (unsigned short*)alloc((size_t)NSLICE * WSL * 2);   // bf16 W^T
  unsigned short* Yall = (unsigned short*)alloc((size_t)NSLICE * NF * 2);  // bf16 Y panels

  hipMemsetAsync(deg, 0, NN * 4, stream);
  hipMemsetAsync(indeg, 0, NN * 4, stream);

  deg_kernel<<<(NE + 255) / 256, 256, 0, stream>>>(ei, deg, indeg);
  dinv_kernel<<<(NN + 255) / 256, 256, 0, stream>>>(deg, dinv);
  scan_kernel<<<1, 256, 0, stream>>>(indeg, rowptr, cursor);
  scatter_kernel<<<(NE + 255) / 256, 256, 0, stream>>>(ei, dinv, cursor, srcarr, wn);
  wtrans_kernel<<<(NSLICE * WSL + 255) / 256, 256, 0, stream>>>(W[0], W[1], W[2], W[3], Wt);
  xcast_kernel<<<(NN * FIN / 4 + 255) / 256, 256, 0, stream>>>(x, xb);

  // 22 GEMMs, XCD-ownership order, split into 3 dispatches (rocprof visibility)
  {
    const int chunk = GEMM_BLOCKS / 3; // 1896
    gemm_mfma_kernel<<<chunk, 256, 0, stream>>>(xb, Wt, Yall, 0);
    gemm_mfma_kernel<<<chunk, 256, 0, stream>>>(xb, Wt, Yall, chunk);
    gemm_mfma_kernel<<<chunk, 256, 0, stream>>>(xb, Wt, Yall, 2 * chunk);
  }

  // ---- Clenshaw schedule (host-side bookkeeping), identical to R3 ----
  const int nK[4] = {4, 5, 6, 7};
  const int st[4] = {0, 4, 9, 15};
  unsigned short* S[4]; // spare panels alias xb (xb no longer needed after GEMM)
  for (int c = 0; c < 4; c++) S[c] = xb + (size_t)c * NF;

  StepA sched[5];
  int nact[5] = {0, 0, 0, 0, 0};
  FinalA fa;

  for (int c = 3; c >= 0; c--) {
    int n = nK[c] - 1;        // Clenshaw degree (props per conv)
    int s0 = 6 - n;           // first global step for this conv
    unsigned short* Yn = Yall + (size_t)(st[c] + n) * NF; // holds b_n = Y_n initially
    unsigned short* A = S[c];
    for (int p = 1; p <= n; p++) {
      int s = s0 + p - 1;
      if (p < n) {
        unsigned short* H = (p & 1) ? Yn : A;
        unsigned short* D = (p & 1) ? A : Yn;
        int j = nact[s]++;
        sched[s].H[j] = H;
        sched[s].Y[j] = Yall + (size_t)(st[c] + n - p) * NF;
        sched[s].P[j] = (p == 1) ? nullptr : D; // in-place over b_{k+2}
        sched[s].D[j] = D;
      } else { // final at s == 5
        int j = 3 - c;
        fa.H[j] = ((n - 1) & 1) ? A : Yn; // loc(b_1)
        fa.P[j] = ((n - 2) & 1) ? A : Yn; // loc(b_2)
        fa.Y[j] = Yall + (size_t)st[c] * NF;
        fa.B[j] = b[c];
        fa.conv[j] = c;
      }
    }
  }

  // pad unused slots with slot 0 (never dereferenced: template bound = nact)
  for (int s = 0; s < 5; s++)
    for (int j = nact[s]; j < 4; j++) {
      sched[s].H[j] = sched[s].H[0];
      sched[s].Y[j] = sched[s].Y[0];
      sched[s].P[j] = sched[s].P[0];
      sched[s].D[j] = sched[s].D[0];
    }

  const int grid_cl = NN / 16; // 625
  for (int s = 0; s < 5; s++) {
    switch (nact[s]) {
      case 1: cl_step_fused<1><<<grid_cl, 576, 0, stream>>>(sched[s], rowptr, srcarr, wn); break;
      case 2: cl_step_fused<2><<<grid_cl, 576, 0, stream>>>(sched[s], rowptr, srcarr, wn); break;
      case 3: cl_step_fused<3><<<grid_cl, 576, 0, stream>>>(sched[s], rowptr, srcarr, wn); break;
      default: cl_step_fused<4><<<grid_cl, 576, 0, stream>>>(sched[s], rowptr, srcarr, wn); break;
    }
  }
  cl_final_fused<<<grid_cl, 576, 0, stream>>>(fa, rowptr, srcarr, wn, out);
}

// Round 8
// 680.245 us; speedup vs baseline: 2.0806x; 1.0704x over previous
//
#include <hip/hip_runtime.h>

#define NN 10000
#define NE 160000
#define FIN 1152
#define FOUT 288
#define FOUT_TOTAL 1152
#define NF (NN * FOUT)          /* 2,880,000 elems per N x 288 panel */
#define WSL (FIN * FOUT)        /* 331,776 elems per (conv,k) weight slice */
#define NSLICE 22
#define NMT 79                  /* mtiles */
#define GEMM_BLOCKS 5688        /* 8 XCD lanes x 711 max work per lane */

typedef __attribute__((ext_vector_type(8))) short short8;
typedef __attribute__((ext_vector_type(8))) unsigned short ushort8v;
typedef __attribute__((ext_vector_type(4))) float floatx4;

__device__ __forceinline__ unsigned short f2bf(float f) {
  unsigned int u = __float_as_uint(f);
  u += 0x7FFF + ((u >> 16) & 1); // round-to-nearest-even
  return (unsigned short)(u >> 16);
}
__device__ __forceinline__ float bf2f(unsigned short u) {
  return __uint_as_float(((unsigned int)u) << 16);
}

// async global->LDS, 16B per lane. LDS dest MUST be wave-uniform base + lane*16.
__device__ __forceinline__ void async_copy16(void* lds, const void* gmem) {
  __builtin_amdgcn_global_load_lds(
      (const __attribute__((address_space(1))) unsigned int*)gmem,
      (__attribute__((address_space(3))) unsigned int*)lds, 16, 0, 0);
}

// ---------------- degree / normalization ----------------

__global__ void deg_kernel(const int* __restrict__ ei, int* __restrict__ deg,
                           int* __restrict__ indeg) {
  int e = blockIdx.x * 256 + threadIdx.x;
  if (e < NE) {
    atomicAdd(&deg[ei[e]], 1);        // out-degree by source (row)
    atomicAdd(&indeg[ei[NE + e]], 1); // in-degree by target (col)
  }
}

__global__ void dinv_kernel(const int* __restrict__ deg, float* __restrict__ dinv) {
  int i = blockIdx.x * 256 + threadIdx.x;
  if (i < NN) {
    int d = deg[i];
    dinv[i] = d > 0 ? rsqrtf((float)d) : 0.0f;
  }
}

// single-block exclusive scan of indeg -> rowptr (and cursor copy)
// R8 rewrite: old version ran ~720 __syncthreads on one block (40 outer x 18
// per ladder) while 255 CUs idle. New: coalesced LDS load -> 40-elem serial
// per-thread sums -> ONE 256-wide Hillis-Steele ladder -> serial exclusive
// within chunk -> coalesced store. ~20 barriers total. Same values.
__global__ __launch_bounds__(256) void scan_kernel(
    const int* __restrict__ indeg, int* __restrict__ rowptr,
    int* __restrict__ cursor) {
  __shared__ int buf[10240]; // 256 threads x 40 elems
  __shared__ int sums[256];
  const int t = threadIdx.x;
  for (int i = t; i < 10240; i += 256) buf[i] = (i < NN) ? indeg[i] : 0;
  __syncthreads();
  const int base = t * 40;
  int tot = 0;
#pragma unroll
  for (int j = 0; j < 40; j++) tot += buf[base + j];
  sums[t] = tot;
  __syncthreads();
  for (int off = 1; off < 256; off <<= 1) {
    int v = (t >= off) ? sums[t - off] : 0;
    __syncthreads();
    sums[t] += v;
    __syncthreads();
  }
  int run = sums[t] - tot; // exclusive prefix of this thread's chunk
#pragma unroll
  for (int j = 0; j < 40; j++) {
    int v = buf[base + j];
    buf[base + j] = run;
    run += v;
  }
  __syncthreads();
  for (int i = t; i < NN; i += 256) {
    int v = buf[i];
    rowptr[i] = v;
    cursor[i] = v;
  }
  if (t == 255) rowptr[NN] = sums[255];
}

__global__ void scatter_kernel(const int* __restrict__ ei, const float* __restrict__ dinv,
                               int* __restrict__ cursor, int* __restrict__ srcarr,
                               float* __restrict__ wn) {
  int e = blockIdx.x * 256 + threadIdx.x;
  if (e < NE) {
    int r = ei[e], c = ei[NE + e];
    int pos = atomicAdd(&cursor[c], 1);
    srcarr[pos] = r;
    wn[pos] = -(dinv[r] * dinv[c]);
  }
}

// ---------------- weight transpose+cast: Wt[slice][o][f] bf16 ----------------
// R8 rewrite: old version read W[k][f][o] with consecutive threads over f ->
// stride-1152B, fully uncoalesced (4B used per 64B line, 64 lines per wave
// load). New: standard 32x32 LDS tiled transpose — coalesced reads (consec o)
// AND coalesced writes (consec f), +1 pad kills bank conflicts. Same values.
__global__ __launch_bounds__(256) void wtrans_kernel(
    const float* __restrict__ W0, const float* __restrict__ W1,
    const float* __restrict__ W2, const float* __restrict__ W3,
    unsigned short* __restrict__ Wt) {
  __shared__ float tile[32][33];
  const int s = blockIdx.y;
  int c, k;
  if (s < 4)       { c = 0; k = s; }
  else if (s < 9)  { c = 1; k = s - 4; }
  else if (s < 15) { c = 2; k = s - 9; }
  else             { c = 3; k = s - 15; }
  const float* W = ((c == 0) ? W0 : (c == 1) ? W1 : (c == 2) ? W2 : W3) +
                   (size_t)k * WSL;
  const int bx = blockIdx.x;          // 0..323 = 36 f-tiles x 9 o-tiles
  const int f0 = (bx % 36) * 32;
  const int o0 = (bx / 36) * 32;
  const int tx = threadIdx.x & 31;
  const int ty = threadIdx.x >> 5;    // 0..7
#pragma unroll
  for (int jj = 0; jj < 4; jj++)
    tile[ty + 8 * jj][tx] = W[(size_t)(f0 + ty + 8 * jj) * FOUT + (o0 + tx)];
  __syncthreads();
  unsigned short* dst = Wt + (size_t)s * WSL;
#pragma unroll
  for (int jj = 0; jj < 4; jj++)
    dst[(size_t)(o0 + ty + 8 * jj) * FIN + (f0 + tx)] = f2bf(tile[tx][ty + 8 * jj]);
}

// ---------------- x -> bf16 cast ----------------
__global__ void xcast_kernel(const float* __restrict__ x, unsigned short* __restrict__ xb) {
  int i = blockIdx.x * 256 + threadIdx.x; // one float4 group per thread
  if (i < NN * FIN / 4) {
    float4 v = *(const float4*)(x + (size_t)i * 4);
    ushort4 r;
    r.x = f2bf(v.x); r.y = f2bf(v.y); r.z = f2bf(v.z); r.w = f2bf(v.w);
    *(ushort4*)(xb + (size_t)i * 4) = r;
  }
}

// ---------------- MFMA GEMM: Y[slice] = bf16( xb @ Wt[slice]^T ) ----------------
// Block tile 128x96, K=1152 (BK=64), 4 waves in 2x2, wave tile 64x48 = 4x3 frags.
// LDS XOR-swizzle verified R2 (conflicts 6.3e7 -> 0). XCD-ownership block order
// verified NEUTRAL (R7: 728.13 vs 728.32) -> MfmaUtil 35.5% is the
// m97-structure ceiling; kept for the (free) L2 behavior. UNCHANGED from R7.
__global__ __launch_bounds__(256) void gemm_mfma_kernel(
    const unsigned short* __restrict__ Xb, const unsigned short* __restrict__ Wt,
    unsigned short* __restrict__ Yall, int Lofs) {
  const int L = Lofs + blockIdx.x;
  const int j = L & 7;                 // XCD lane (round-robin heuristic)
  const int m = L >> 3;                // work index within XCD lane
  const int nsl = (j < 6) ? 3 : 2;     // slices owned by this lane
  const int work = nsl * 3 * NMT;
  if (m >= work) return;               // uniform early-out, before barriers
  const int mtile = m / (nsl * 3);
  const int rem = m - mtile * (nsl * 3);
  const int slice = j + 8 * (rem / 3); // j<6: {j,j+8,j+16}; j>=6: {j,j+8}
  const int n0 = (rem % 3) * 96;
  const int m0 = mtile * 128;

  __shared__ unsigned short As[128][64]; // [m][k] rows of 128 B (chunk-swizzled)
  __shared__ unsigned short Bs[96][64];  // [o][f] (chunk-swizzled)

  const int tid = threadIdx.x;
  const int lane = tid & 63;
  const int wave = tid >> 6;
  const int wx = wave & 1;        // n-dir
  const int wy = wave >> 1;       // m-dir
  const int lm = lane & 15;
  const int hi = lane >> 4;       // 16B chunk sub-index within 64B k-phase

  floatx4 acc[4][3];
#pragma unroll
  for (int i = 0; i < 4; i++)
#pragma unroll
    for (int jj = 0; jj < 3; jj++) acc[i][jj] = (floatx4){0.f, 0.f, 0.f, 0.f};

  const unsigned short* Wbase = Wt + (size_t)slice * WSL;

  for (int f0 = 0; f0 < FIN; f0 += 64) {
    __syncthreads(); // protect LDS from previous iteration's readers
    // stage A: 128 rows x 128 B, lane-linear LDS dest, swizzled global source
#pragma unroll
    for (int i = 0; i < 4; i++) {
      int idx = i * 256 + tid;
      int row = idx >> 3;
      int ck = idx & 7;
      int gr = m0 + row;
      gr = gr < NN ? gr : NN - 1; // clamp (masked at store)
      async_copy16((char*)&As[0][0] + idx * 16,
                   (const char*)Xb + ((size_t)gr * FIN + f0) * 2 + ((ck ^ (row & 7)) << 4));
    }
    // stage B: 96 rows x 128 B
#pragma unroll
    for (int i = 0; i < 3; i++) {
      int idx = i * 256 + tid;
      int row = idx >> 3;
      int ck = idx & 7;
      async_copy16((char*)&Bs[0][0] + idx * 16,
                   (const char*)Wbase + ((size_t)(n0 + row) * FIN + f0) * 2 + ((ck ^ (row & 7)) << 4));
    }
    __syncthreads();
#pragma unroll
    for (int s = 0; s < 2; s++) {
      short8 a[4], b[3];
#pragma unroll
      for (int i = 0; i < 4; i++) {
        int ar = wy * 64 + i * 16 + lm;
        a[i] = *(const short8*)((const char*)&As[ar][0] + (((s * 4 + hi) ^ (ar & 7)) << 4));
      }
#pragma unroll
      for (int jj = 0; jj < 3; jj++) {
        int br = wx * 48 + jj * 16 + lm;
        b[jj] = *(const short8*)((const char*)&Bs[br][0] + (((s * 4 + hi) ^ (br & 7)) << 4));
      }
#pragma unroll
      for (int i = 0; i < 4; i++)
#pragma unroll
        for (int jj = 0; jj < 3; jj++)
          acc[i][jj] = __builtin_amdgcn_mfma_f32_16x16x32_bf16(a[i], b[jj], acc[i][jj], 0, 0, 0);
    }
  }
  // epilogue: C/D layout col=lane&15, row=(lane>>4)*4+reg -> bf16 Y panel
  unsigned short* Yb = Yall + (size_t)slice * NF;
  const int cbase = n0 + wx * 48 + lm;
  const int rbase = (lane >> 4) * 4;
#pragma unroll
  for (int i = 0; i < 4; i++) {
#pragma unroll
    for (int r = 0; r < 4; r++) {
      int grow = m0 + wy * 64 + i * 16 + rbase + r;
      if (grow < NN) {
        unsigned short* op = Yb + (size_t)grow * FOUT + cbase;
#pragma unroll
        for (int jj = 0; jj < 3; jj++) op[jj * 16] = f2bf(acc[i][jj][r]);
      }
    }
  }
}

// ---------------- Clenshaw steps (slot-FUSED; verified R3/R7 bodies) ----------
// b_k = Y_k + 2*L*b_{k+1} - b_{k+2}   (all N x 288 bf16 panels; fp32 accumulate)
// Block: 576 threads = 16 nodes x 36 lanes, 16B (8 bf16) per lane.
// R7 measured (nact=4): 69.4 us, FETCH 190 MB = 8-XCD replication of the
// 23 MB panel set, HBM 3.1 TB/s, VALUBusy 23%, Occ 18%. UNCHANGED this round.

struct StepA {
  const unsigned short* H[4]; // gather source  b_{k+1}  (per slot)
  const unsigned short* Y[4]; // additive Y_k
  const unsigned short* P[4]; // b_{k+2} (may be null; uniform branch)
  unsigned short* D[4];       // dest b_k
};

template <int NACT>
__global__ __launch_bounds__(576) void cl_step_fused(
    StepA a, const int* __restrict__ rowptr, const int* __restrict__ srcarr,
    const float* __restrict__ wn) {
  const int t = threadIdx.x;
  const int ln = t % 36;
  const int node = blockIdx.x * 16 + t / 36;
  if (node >= NN) return;
  const int off = ln * 8;
  const int rs = rowptr[node];
  const int re = rowptr[node + 1];
  float acc[NACT][8];
#pragma unroll
  for (int s = 0; s < NACT; s++)
#pragma unroll
    for (int q = 0; q < 8; q++) acc[s][q] = 0.f;

  constexpr int U = (NACT <= 2) ? 4 : 2; // edge unroll: keep ~8 loads in flight
  int p = rs;
  for (; p + U <= re; p += U) {
    int r[U];
    float w[U];
#pragma unroll
    for (int u = 0; u < U; u++) { r[u] = srcarr[p + u]; w[u] = wn[p + u]; }
    ushort8v h[U][NACT];
#pragma unroll
    for (int u = 0; u < U; u++)
#pragma unroll
      for (int s = 0; s < NACT; s++)
        h[u][s] = *(const ushort8v*)(a.H[s] + (size_t)r[u] * FOUT + off);
#pragma unroll
    for (int u = 0; u < U; u++)
#pragma unroll
      for (int s = 0; s < NACT; s++)
#pragma unroll
        for (int q = 0; q < 8; q++) acc[s][q] += w[u] * bf2f(h[u][s][q]);
  }
  for (; p < re; ++p) {
    int r = srcarr[p];
    float w = wn[p];
#pragma unroll
    for (int s = 0; s < NACT; s++) {
      ushort8v hh = *(const ushort8v*)(a.H[s] + (size_t)r * FOUT + off);
#pragma unroll
      for (int q = 0; q < 8; q++) acc[s][q] += w * bf2f(hh[q]);
    }
  }

  size_t o = (size_t)node * FOUT + off;
#pragma unroll
  for (int s = 0; s < NACT; s++) {
    ushort8v y = *(const ushort8v*)(a.Y[s] + o);
    ushort8v d;
    if (a.P[s]) {
      ushort8v pp = *(const ushort8v*)(a.P[s] + o);
#pragma unroll
      for (int q = 0; q < 8; q++) d[q] = f2bf(bf2f(y[q]) + 2.f * acc[s][q] - bf2f(pp[q]));
    } else {
#pragma unroll
      for (int q = 0; q < 8; q++) d[q] = f2bf(bf2f(y[q]) + 2.f * acc[s][q]);
    }
    *(ushort8v*)(a.D[s] + o) = d;
  }
}

// final: out[:, c*288 + f] = bias[f] + Y_0 + L*b_1 - b_2 (fp32 out), all 4 convs fused
struct FinalA {
  const unsigned short* H[4]; // b_1
  const unsigned short* Y[4]; // Y_0
  const unsigned short* P[4]; // b_2
  const float* B[4];          // bias
  int conv[4];
};

__global__ __launch_bounds__(576) void cl_final_fused(
    FinalA a, const int* __restrict__ rowptr, const int* __restrict__ srcarr,
    const float* __restrict__ wn, float* __restrict__ out) {
  const int t = threadIdx.x;
  const int ln = t % 36;
  const int node = blockIdx.x * 16 + t / 36;
  if (node >= NN) return;
  const int off = ln * 8;
  const int rs = rowptr[node];
  const int re = rowptr[node + 1];
  float acc[4][8];
#pragma unroll
  for (int s = 0; s < 4; s++)
#pragma unroll
    for (int q = 0; q < 8; q++) acc[s][q] = 0.f;

  constexpr int U = 2;
  int p = rs;
  for (; p + U <= re; p += U) {
    int r[U];
    float w[U];
#pragma unroll
    for (int u = 0; u < U; u++) { r[u] = srcarr[p + u]; w[u] = wn[p + u]; }
    ushort8v h[U][4];
#pragma unroll
    for (int u = 0; u < U; u++)
#pragma unroll
      for (int s = 0; s < 4; s++)
        h[u][s] = *(const ushort8v*)(a.H[s] + (size_t)r[u] * FOUT + off);
#pragma unroll
    for (int u = 0; u < U; u++)
#pragma unroll
      for (int s = 0; s < 4; s++)
#pragma unroll
        for (int q = 0; q < 8; q++) acc[s][q] += w[u] * bf2f(h[u][s][q]);
  }
  for (; p < re; ++p) {
    int r = srcarr[p];
    float w = wn[p];
#pragma unroll
    for (int s = 0; s < 4; s++) {
      ushort8v hh = *(const ushort8v*)(a.H[s] + (size_t)r * FOUT + off);
#pragma unroll
      for (int q = 0; q < 8; q++) acc[s][q] += w * bf2f(hh[q]);
    }
  }

  size_t o = (size_t)node * FOUT + off;
#pragma unroll
  for (int s = 0; s < 4; s++) {
    ushort8v y = *(const ushort8v*)(a.Y[s] + o);
    ushort8v pp = *(const ushort8v*)(a.P[s] + o);
    const float* bias = a.B[s] + off;
    float r8[8];
#pragma unroll
    for (int q = 0; q < 8; q++)
      r8[q] = bias[q] + bf2f(y[q]) + acc[s][q] - bf2f(pp[q]);
    float* op = out + (size_t)node * FOUT_TOTAL + a.conv[s] * FOUT + off;
    *(float4*)(op + 0) = make_float4(r8[0], r8[1], r8[2], r8[3]);
    *(float4*)(op + 4) = make_float4(r8[4], r8[5], r8[6], r8[7]);
  }
}

// ---------------- launch ----------------

extern "C" void kernel_launch(void* const* d_in, const int* in_sizes, int n_in,
                              void* d_out, int out_size, void* d_ws, size_t ws_size,
                              hipStream_t stream) {
  const float* x = (const float*)d_in[0];
  const int* ei = (const int*)d_in[1];
  const float* W[4] = {(const float*)d_in[2], (const float*)d_in[4],
                       (const float*)d_in[6], (const float*)d_in[8]};
  const float* b[4] = {(const float*)d_in[3], (const float*)d_in[5],
                       (const float*)d_in[7], (const float*)d_in[9]};
  float* out = (float*)d_out;

  char* ws = (char*)d_ws;
  size_t off = 0;
  auto alloc = [&](size_t bytes) -> char* {
    char* p = ws + off;
    off += (bytes + 255) & ~(size_t)255;
    return p;
  };
  int* deg = (int*)alloc(NN * 4);
  int* indeg = (int*)alloc(NN * 4);
  int* rowptr = (int*)alloc((NN + 1) * 4);
  int* cursor = (int*)alloc(NN * 4);
  int* srcarr = (int*)alloc(NE * 4);
  float* wn = (float*)alloc(NE * 4);
  float* dinv = (float*)alloc(NN * 4);
  unsigned short* xb = (unsigned short*)alloc((size_t)NN * FIN * 2);       // bf16 x; reused as 4 spare panels
  unsigned short* Wt = (unsigned short*)alloc((size_t)NSLICE * WSL * 2);   // bf16 W^T
  unsigned short* Yall = (unsigned short*)alloc((size_t)NSLICE * NF * 2);  // bf16 Y panels

  hipMemsetAsync(deg, 0, NN * 4, stream);
  hipMemsetAsync(indeg, 0, NN * 4, stream);

  deg_kernel<<<(NE + 255) / 256, 256, 0, stream>>>(ei, deg, indeg);
  dinv_kernel<<<(NN + 255) / 256, 256, 0, stream>>>(deg, dinv);
  scan_kernel<<<1, 256, 0, stream>>>(indeg, rowptr, cursor);
  scatter_kernel<<<(NE + 255) / 256, 256, 0, stream>>>(ei, dinv, cursor, srcarr, wn);
  wtrans_kernel<<<dim3(324, NSLICE), 256, 0, stream>>>(W[0], W[1], W[2], W[3], Wt);
  xcast_kernel<<<(NN * FIN / 4 + 255) / 256, 256, 0, stream>>>(x, xb);

  // 22 GEMMs, XCD-ownership order, split into 3 dispatches (rocprof visibility)
  {
    const int chunk = GEMM_BLOCKS / 3; // 1896
    gemm_mfma_kernel<<<chunk, 256, 0, stream>>>(xb, Wt, Yall, 0);
    gemm_mfma_kernel<<<chunk, 256, 0, stream>>>(xb, Wt, Yall, chunk);
    gemm_mfma_kernel<<<chunk, 256, 0, stream>>>(xb, Wt, Yall, 2 * chunk);
  }

  // ---- Clenshaw schedule (host-side bookkeeping), identical to R3/R7 ----
  const int nK[4] = {4, 5, 6, 7};
  const int st[4] = {0, 4, 9, 15};
  unsigned short* S[4]; // spare panels alias xb (xb no longer needed after GEMM)
  for (int c = 0; c < 4; c++) S[c] = xb + (size_t)c * NF;

  StepA sched[5];
  int nact[5] = {0, 0, 0, 0, 0};
  FinalA fa;

  for (int c = 3; c >= 0; c--) {
    int n = nK[c] - 1;        // Clenshaw degree (props per conv)
    int s0 = 6 - n;           // first global step for this conv
    unsigned short* Yn = Yall + (size_t)(st[c] + n) * NF; // holds b_n = Y_n initially
    unsigned short* A = S[c];
    for (int p = 1; p <= n; p++) {
      int s = s0 + p - 1;
      if (p < n) {
        unsigned short* H = (p & 1) ? Yn : A;
        unsigned short* D = (p & 1) ? A : Yn;
        int j = nact[s]++;
        sched[s].H[j] = H;
        sched[s].Y[j] = Yall + (size_t)(st[c] + n - p) * NF;
        sched[s].P[j] = (p == 1) ? nullptr : D; // in-place over b_{k+2}
        sched[s].D[j] = D;
      } else { // final at s == 5
        int j = 3 - c;
        fa.H[j] = ((n - 1) & 1) ? A : Yn; // loc(b_1)
        fa.P[j] = ((n - 2) & 1) ? A : Yn; // loc(b_2)
        fa.Y[j] = Yall + (size_t)st[c] * NF;
        fa.B[j] = b[c];
        fa.conv[j] = c;
      }
    }
  }

  // pad unused slots with slot 0 (never dereferenced: template bound = nact)
  for (int s = 0; s < 5; s++)
    for (int j = nact[s]; j < 4; j++) {
      sched[s].H[j] = sched[s].H[0];
      sched[s].Y[j] = sched[s].Y[0];
      sched[s].P[j] = sched[s].P[0];
      sched[s].D[j] = sched[s].D[0];
    }

  const int grid_cl = NN / 16; // 625
  for (int s = 0; s < 5; s++) {
    switch (nact[s]) {
      case 1: cl_step_fused<1><<<grid_cl, 576, 0, stream>>>(sched[s], rowptr, srcarr, wn); break;
      case 2: cl_step_fused<2><<<grid_cl, 576, 0, stream>>>(sched[s], rowptr, srcarr, wn); break;
      case 3: cl_step_fused<3><<<grid_cl, 576, 0, stream>>>(sched[s], rowptr, srcarr, wn); break;
      default: cl_step_fused<4><<<grid_cl, 576, 0, stream>>>(sched[s], rowptr, srcarr, wn); break;
    }
  }
  cl_final_fused<<<grid_cl, 576, 0, stream>>>(fa, rowptr, srcarr, wn, out);
}

// Round 9
// 657.109 us; speedup vs baseline: 2.1539x; 1.0352x over previous
//
#include <hip/hip_runtime.h>

#define NN 10000
#define NE 160000
#define FIN 1152
#define FOUT 288
#define FOUT_TOTAL 1152
#define NF (NN * FOUT)          /* 2,880,000 elems per N x 288 panel */
#define WSL (FIN * FOUT)        /* 331,776 elems per (conv,k) weight slice */
#define NSLICE 22
#define NMT 79                  /* mtiles */
#define GEMM_BLOCKS 5688        /* 8 XCD lanes x 711 max work per lane */

typedef __attribute__((ext_vector_type(8))) short short8;
typedef __attribute__((ext_vector_type(8))) unsigned short ushort8v;
typedef __attribute__((ext_vector_type(4))) float floatx4;

__device__ __forceinline__ unsigned short f2bf(float f) {
  unsigned int u = __float_as_uint(f);
  u += 0x7FFF + ((u >> 16) & 1); // round-to-nearest-even
  return (unsigned short)(u >> 16);
}
__device__ __forceinline__ float bf2f(unsigned short u) {
  return __uint_as_float(((unsigned int)u) << 16);
}

// async global->LDS, 16B per lane. LDS dest MUST be wave-uniform base + lane*16.
__device__ __forceinline__ void async_copy16(void* lds, const void* gmem) {
  __builtin_amdgcn_global_load_lds(
      (const __attribute__((address_space(1))) unsigned int*)gmem,
      (__attribute__((address_space(3))) unsigned int*)lds, 16, 0, 0);
}

// ---------------- degree / normalization ----------------

__global__ void deg_kernel(const int* __restrict__ ei, int* __restrict__ deg,
                           int* __restrict__ indeg) {
  int e = blockIdx.x * 256 + threadIdx.x;
  if (e < NE) {
    atomicAdd(&deg[ei[e]], 1);        // out-degree by source (row)
    atomicAdd(&indeg[ei[NE + e]], 1); // in-degree by target (col)
  }
}

__global__ void dinv_kernel(const int* __restrict__ deg, float* __restrict__ dinv) {
  int i = blockIdx.x * 256 + threadIdx.x;
  if (i < NN) {
    int d = deg[i];
    dinv[i] = d > 0 ? rsqrtf((float)d) : 0.0f;
  }
}

// single-block exclusive scan of indeg -> rowptr (verified R8: ~20 barriers)
__global__ __launch_bounds__(256) void scan_kernel(
    const int* __restrict__ indeg, int* __restrict__ rowptr,
    int* __restrict__ cursor) {
  __shared__ int buf[10240]; // 256 threads x 40 elems
  __shared__ int sums[256];
  const int t = threadIdx.x;
  for (int i = t; i < 10240; i += 256) buf[i] = (i < NN) ? indeg[i] : 0;
  __syncthreads();
  const int base = t * 40;
  int tot = 0;
#pragma unroll
  for (int j = 0; j < 40; j++) tot += buf[base + j];
  sums[t] = tot;
  __syncthreads();
  for (int off = 1; off < 256; off <<= 1) {
    int v = (t >= off) ? sums[t - off] : 0;
    __syncthreads();
    sums[t] += v;
    __syncthreads();
  }
  int run = sums[t] - tot; // exclusive prefix of this thread's chunk
#pragma unroll
  for (int j = 0; j < 40; j++) {
    int v = buf[base + j];
    buf[base + j] = run;
    run += v;
  }
  __syncthreads();
  for (int i = t; i < NN; i += 256) {
    int v = buf[i];
    rowptr[i] = v;
    cursor[i] = v;
  }
  if (t == 255) rowptr[NN] = sums[255];
}

__global__ void scatter_kernel(const int* __restrict__ ei, const float* __restrict__ dinv,
                               int* __restrict__ cursor, int* __restrict__ srcarr,
                               float* __restrict__ wn) {
  int e = blockIdx.x * 256 + threadIdx.x;
  if (e < NE) {
    int r = ei[e], c = ei[NE + e];
    int pos = atomicAdd(&cursor[c], 1);
    srcarr[pos] = r;
    wn[pos] = -(dinv[r] * dinv[c]);
  }
}

// ---------------- weight transpose+cast (verified R8: 32x32 LDS tiled) --------
__global__ __launch_bounds__(256) void wtrans_kernel(
    const float* __restrict__ W0, const float* __restrict__ W1,
    const float* __restrict__ W2, const float* __restrict__ W3,
    unsigned short* __restrict__ Wt) {
  __shared__ float tile[32][33];
  const int s = blockIdx.y;
  int c, k;
  if (s < 4)       { c = 0; k = s; }
  else if (s < 9)  { c = 1; k = s - 4; }
  else if (s < 15) { c = 2; k = s - 9; }
  else             { c = 3; k = s - 15; }
  const float* W = ((c == 0) ? W0 : (c == 1) ? W1 : (c == 2) ? W2 : W3) +
                   (size_t)k * WSL;
  const int bx = blockIdx.x;          // 0..323 = 36 f-tiles x 9 o-tiles
  const int f0 = (bx % 36) * 32;
  const int o0 = (bx / 36) * 32;
  const int tx = threadIdx.x & 31;
  const int ty = threadIdx.x >> 5;    // 0..7
#pragma unroll
  for (int jj = 0; jj < 4; jj++)
    tile[ty + 8 * jj][tx] = W[(size_t)(f0 + ty + 8 * jj) * FOUT + (o0 + tx)];
  __syncthreads();
  unsigned short* dst = Wt + (size_t)s * WSL;
#pragma unroll
  for (int jj = 0; jj < 4; jj++)
    dst[(size_t)(o0 + ty + 8 * jj) * FIN + (f0 + tx)] = f2bf(tile[tx][ty + 8 * jj]);
}

// ---------------- x -> bf16 cast ----------------
__global__ void xcast_kernel(const float* __restrict__ x, unsigned short* __restrict__ xb) {
  int i = blockIdx.x * 256 + threadIdx.x; // one float4 group per thread
  if (i < NN * FIN / 4) {
    float4 v = *(const float4*)(x + (size_t)i * 4);
    ushort4 r;
    r.x = f2bf(v.x); r.y = f2bf(v.y); r.z = f2bf(v.z); r.w = f2bf(v.w);
    *(ushort4*)(xb + (size_t)i * 4) = r;
  }
}

// ---------------- MFMA GEMM: Y[slice] = bf16( xb @ Wt[slice]^T ) ----------------
// Block tile 128x96, K=1152 (BK=64), 4 waves in 2x2, wave tile 64x48 = 4x3 frags.
// LDS XOR-swizzle verified R2 (conflicts 6.3e7 -> 0); XCD-ownership order
// verified neutral R7 (kept, free). MfmaUtil 35.5% = m97-structure ceiling.
// R9: merged back to ONE dispatch (the 3-split was rocprof-visibility only;
// saves 2 full-grid drains). Inner body UNCHANGED.
__global__ __launch_bounds__(256) void gemm_mfma_kernel(
    const unsigned short* __restrict__ Xb, const unsigned short* __restrict__ Wt,
    unsigned short* __restrict__ Yall) {
  const int L = blockIdx.x;
  const int j = L & 7;                 // XCD lane (round-robin heuristic)
  const int m = L >> 3;                // work index within XCD lane
  const int nsl = (j < 6) ? 3 : 2;     // slices owned by this lane
  const int work = nsl * 3 * NMT;
  if (m >= work) return;               // uniform early-out, before barriers
  const int mtile = m / (nsl * 3);
  const int rem = m - mtile * (nsl * 3);
  const int slice = j + 8 * (rem / 3); // j<6: {j,j+8,j+16}; j>=6: {j,j+8}
  const int n0 = (rem % 3) * 96;
  const int m0 = mtile * 128;

  __shared__ unsigned short As[128][64]; // [m][k] rows of 128 B (chunk-swizzled)
  __shared__ unsigned short Bs[96][64];  // [o][f] (chunk-swizzled)

  const int tid = threadIdx.x;
  const int lane = tid & 63;
  const int wave = tid >> 6;
  const int wx = wave & 1;        // n-dir
  const int wy = wave >> 1;       // m-dir
  const int lm = lane & 15;
  const int hi = lane >> 4;       // 16B chunk sub-index within 64B k-phase

  floatx4 acc[4][3];
#pragma unroll
  for (int i = 0; i < 4; i++)
#pragma unroll
    for (int jj = 0; jj < 3; jj++) acc[i][jj] = (floatx4){0.f, 0.f, 0.f, 0.f};

  const unsigned short* Wbase = Wt + (size_t)slice * WSL;

  for (int f0 = 0; f0 < FIN; f0 += 64) {
    __syncthreads(); // protect LDS from previous iteration's readers
    // stage A: 128 rows x 128 B, lane-linear LDS dest, swizzled global source
#pragma unroll
    for (int i = 0; i < 4; i++) {
      int idx = i * 256 + tid;
      int row = idx >> 3;
      int ck = idx & 7;
      int gr = m0 + row;
      gr = gr < NN ? gr : NN - 1; // clamp (masked at store)
      async_copy16((char*)&As[0][0] + idx * 16,
                   (const char*)Xb + ((size_t)gr * FIN + f0) * 2 + ((ck ^ (row & 7)) << 4));
    }
    // stage B: 96 rows x 128 B
#pragma unroll
    for (int i = 0; i < 3; i++) {
      int idx = i * 256 + tid;
      int row = idx >> 3;
      int ck = idx & 7;
      async_copy16((char*)&Bs[0][0] + idx * 16,
                   (const char*)Wbase + ((size_t)(n0 + row) * FIN + f0) * 2 + ((ck ^ (row & 7)) << 4));
    }
    __syncthreads();
#pragma unroll
    for (int s = 0; s < 2; s++) {
      short8 a[4], b[3];
#pragma unroll
      for (int i = 0; i < 4; i++) {
        int ar = wy * 64 + i * 16 + lm;
        a[i] = *(const short8*)((const char*)&As[ar][0] + (((s * 4 + hi) ^ (ar & 7)) << 4));
      }
#pragma unroll
      for (int jj = 0; jj < 3; jj++) {
        int br = wx * 48 + jj * 16 + lm;
        b[jj] = *(const short8*)((const char*)&Bs[br][0] + (((s * 4 + hi) ^ (br & 7)) << 4));
      }
#pragma unroll
      for (int i = 0; i < 4; i++)
#pragma unroll
        for (int jj = 0; jj < 3; jj++)
          acc[i][jj] = __builtin_amdgcn_mfma_f32_16x16x32_bf16(a[i], b[jj], acc[i][jj], 0, 0, 0);
    }
  }
  // epilogue: C/D layout col=lane&15, row=(lane>>4)*4+reg -> bf16 Y panel
  unsigned short* Yb = Yall + (size_t)slice * NF;
  const int cbase = n0 + wx * 48 + lm;
  const int rbase = (lane >> 4) * 4;
#pragma unroll
  for (int i = 0; i < 4; i++) {
#pragma unroll
    for (int r = 0; r < 4; r++) {
      int grow = m0 + wy * 64 + i * 16 + rbase + r;
      if (grow < NN) {
        unsigned short* op = Yb + (size_t)grow * FOUT + cbase;
#pragma unroll
        for (int jj = 0; jj < 3; jj++) op[jj * 16] = f2bf(acc[i][jj][r]);
      }
    }
  }
}

// ---------------- Clenshaw steps: slot-fused + EDGE-SPLIT partner lanes --------
// b_k = Y_k + 2*L*b_{k+1} - b_{k+2}   (N x 288 bf16 panels; fp32 accumulate)
// R8 counters (nact=4): 69.5 us, HBM 39%, VALU 23%, Occ 18% -> latency-bound
// under-concurrency, NOT BW/VALU-bound. R3 showed per-thread unroll costs VGPR;
// the free axis is MORE THREADS: split each node's edge list across 2 partner
// lanes (t^1, always same wave). Same VGPR, 2x aggregate in-flight gathers,
// grid 625 -> 1250 blocks (44 waves/CU demanded -> saturates the 32 cap).
// Partners combine via 32 __shfl_xor adds; even lane writes. fp32 sum now
// (first half)+(second half) — bf16-dominated absmax unaffected.
// Block: 576 threads = 8 nodes x 36 lanes x 2 edge-halves.

struct StepA {
  const unsigned short* H[4]; // gather source  b_{k+1}  (per slot)
  const unsigned short* Y[4]; // additive Y_k
  const unsigned short* P[4]; // b_{k+2} (may be null; uniform branch)
  unsigned short* D[4];       // dest b_k
};

template <int NACT>
__global__ __launch_bounds__(576) void cl_step_fused(
    StepA a, const int* __restrict__ rowptr, const int* __restrict__ srcarr,
    const float* __restrict__ wn) {
  const int t = threadIdx.x;
  const int nodesub = t / 72;
  const int rem = t - nodesub * 72;
  const int ln = rem >> 1;
  const int half = rem & 1;
  const int node = blockIdx.x * 8 + nodesub; // grid 1250 x 8 = 10000 exact
  const int off = ln * 8;
  const int rs0 = rowptr[node];
  const int re0 = rowptr[node + 1];
  const int mid = rs0 + ((re0 - rs0 + 1) >> 1);
  const int rs = half ? mid : rs0;
  const int re = half ? re0 : mid;
  float acc[NACT][8];
#pragma unroll
  for (int s = 0; s < NACT; s++)
#pragma unroll
    for (int q = 0; q < 8; q++) acc[s][q] = 0.f;

  constexpr int U = (NACT <= 2) ? 4 : 2; // edge unroll
  int p = rs;
  for (; p + U <= re; p += U) {
    int r[U];
    float w[U];
#pragma unroll
    for (int u = 0; u < U; u++) { r[u] = srcarr[p + u]; w[u] = wn[p + u]; }
    ushort8v h[U][NACT];
#pragma unroll
    for (int u = 0; u < U; u++)
#pragma unroll
      for (int s = 0; s < NACT; s++)
        h[u][s] = *(const ushort8v*)(a.H[s] + (size_t)r[u] * FOUT + off);
#pragma unroll
    for (int u = 0; u < U; u++)
#pragma unroll
      for (int s = 0; s < NACT; s++)
#pragma unroll
        for (int q = 0; q < 8; q++) acc[s][q] += w[u] * bf2f(h[u][s][q]);
  }
  for (; p < re; ++p) {
    int r = srcarr[p];
    float w = wn[p];
#pragma unroll
    for (int s = 0; s < NACT; s++) {
      ushort8v hh = *(const ushort8v*)(a.H[s] + (size_t)r * FOUT + off);
#pragma unroll
      for (int q = 0; q < 8; q++) acc[s][q] += w * bf2f(hh[q]);
    }
  }

  // partner combine (t^1, same wave by construction)
#pragma unroll
  for (int s = 0; s < NACT; s++)
#pragma unroll
    for (int q = 0; q < 8; q++) acc[s][q] += __shfl_xor(acc[s][q], 1, 64);

  if (half == 0) {
    size_t o = (size_t)node * FOUT + off;
#pragma unroll
    for (int s = 0; s < NACT; s++) {
      ushort8v y = *(const ushort8v*)(a.Y[s] + o);
      ushort8v d;
      if (a.P[s]) {
        ushort8v pp = *(const ushort8v*)(a.P[s] + o);
#pragma unroll
        for (int q = 0; q < 8; q++)
          d[q] = f2bf(bf2f(y[q]) + 2.f * acc[s][q] - bf2f(pp[q]));
      } else {
#pragma unroll
        for (int q = 0; q < 8; q++) d[q] = f2bf(bf2f(y[q]) + 2.f * acc[s][q]);
      }
      *(ushort8v*)(a.D[s] + o) = d;
    }
  }
}

// final: out[:, c*288 + f] = bias[f] + Y_0 + L*b_1 - b_2 (fp32 out), 4 convs fused
struct FinalA {
  const unsigned short* H[4]; // b_1
  const unsigned short* Y[4]; // Y_0
  const unsigned short* P[4]; // b_2
  const float* B[4];          // bias
  int conv[4];
};

__global__ __launch_bounds__(576) void cl_final_fused(
    FinalA a, const int* __restrict__ rowptr, const int* __restrict__ srcarr,
    const float* __restrict__ wn, float* __restrict__ out) {
  const int t = threadIdx.x;
  const int nodesub = t / 72;
  const int rem = t - nodesub * 72;
  const int ln = rem >> 1;
  const int half = rem & 1;
  const int node = blockIdx.x * 8 + nodesub;
  const int off = ln * 8;
  const int rs0 = rowptr[node];
  const int re0 = rowptr[node + 1];
  const int mid = rs0 + ((re0 - rs0 + 1) >> 1);
  const int rs = half ? mid : rs0;
  const int re = half ? re0 : mid;
  float acc[4][8];
#pragma unroll
  for (int s = 0; s < 4; s++)
#pragma unroll
    for (int q = 0; q < 8; q++) acc[s][q] = 0.f;

  constexpr int U = 2;
  int p = rs;
  for (; p + U <= re; p += U) {
    int r[U];
    float w[U];
#pragma unroll
    for (int u = 0; u < U; u++) { r[u] = srcarr[p + u]; w[u] = wn[p + u]; }
    ushort8v h[U][4];
#pragma unroll
    for (int u = 0; u < U; u++)
#pragma unroll
      for (int s = 0; s < 4; s++)
        h[u][s] = *(const ushort8v*)(a.H[s] + (size_t)r[u] * FOUT + off);
#pragma unroll
    for (int u = 0; u < U; u++)
#pragma unroll
      for (int s = 0; s < 4; s++)
#pragma unroll
        for (int q = 0; q < 8; q++) acc[s][q] += w[u] * bf2f(h[u][s][q]);
  }
  for (; p < re; ++p) {
    int r = srcarr[p];
    float w = wn[p];
#pragma unroll
    for (int s = 0; s < 4; s++) {
      ushort8v hh = *(const ushort8v*)(a.H[s] + (size_t)r * FOUT + off);
#pragma unroll
      for (int q = 0; q < 8; q++) acc[s][q] += w * bf2f(hh[q]);
    }
  }

#pragma unroll
  for (int s = 0; s < 4; s++)
#pragma unroll
    for (int q = 0; q < 8; q++) acc[s][q] += __shfl_xor(acc[s][q], 1, 64);

  if (half == 0) {
    size_t o = (size_t)node * FOUT + off;
#pragma unroll
    for (int s = 0; s < 4; s++) {
      ushort8v y = *(const ushort8v*)(a.Y[s] + o);
      ushort8v pp = *(const ushort8v*)(a.P[s] + o);
      const float* bias = a.B[s] + off;
      float r8[8];
#pragma unroll
      for (int q = 0; q < 8; q++)
        r8[q] = bias[q] + bf2f(y[q]) + acc[s][q] - bf2f(pp[q]);
      float* op = out + (size_t)node * FOUT_TOTAL + a.conv[s] * FOUT + off;
      *(float4*)(op + 0) = make_float4(r8[0], r8[1], r8[2], r8[3]);
      *(float4*)(op + 4) = make_float4(r8[4], r8[5], r8[6], r8[7]);
    }
  }
}

// ---------------- launch ----------------

extern "C" void kernel_launch(void* const* d_in, const int* in_sizes, int n_in,
                              void* d_out, int out_size, void* d_ws, size_t ws_size,
                              hipStream_t stream) {
  const float* x = (const float*)d_in[0];
  const int* ei = (const int*)d_in[1];
  const float* W[4] = {(const float*)d_in[2], (const float*)d_in[4],
                       (const float*)d_in[6], (const float*)d_in[8]};
  const float* b[4] = {(const float*)d_in[3], (const float*)d_in[5],
                       (const float*)d_in[7], (const float*)d_in[9]};
  float* out = (float*)d_out;

  char* ws = (char*)d_ws;
  size_t off = 0;
  auto alloc = [&](size_t bytes) -> char* {
    char* p = ws + off;
    off += (bytes + 255) & ~(size_t)255;
    return p;
  };
  int* deg = (int*)alloc(NN * 4);
  int* indeg = (int*)alloc(NN * 4);
  int* rowptr = (int*)alloc((NN + 1) * 4);
  int* cursor = (int*)alloc(NN * 4);
  int* srcarr = (int*)alloc(NE * 4);
  float* wn = (float*)alloc(NE * 4);
  float* dinv = (float*)alloc(NN * 4);
  unsigned short* xb = (unsigned short*)alloc((size_t)NN * FIN * 2);       // bf16 x; reused as 4 spare panels
  unsigned short* Wt = (unsigned short*)alloc((size_t)NSLICE * WSL * 2);   // bf16 W^T
  unsigned short* Yall = (unsigned short*)alloc((size_t)NSLICE * NF * 2);  // bf16 Y panels

  hipMemsetAsync(deg, 0, NN * 4, stream);
  hipMemsetAsync(indeg, 0, NN * 4, stream);

  deg_kernel<<<(NE + 255) / 256, 256, 0, stream>>>(ei, deg, indeg);
  dinv_kernel<<<(NN + 255) / 256, 256, 0, stream>>>(deg, dinv);
  scan_kernel<<<1, 256, 0, stream>>>(indeg, rowptr, cursor);
  scatter_kernel<<<(NE + 255) / 256, 256, 0, stream>>>(ei, dinv, cursor, srcarr, wn);
  wtrans_kernel<<<dim3(324, NSLICE), 256, 0, stream>>>(W[0], W[1], W[2], W[3], Wt);
  xcast_kernel<<<(NN * FIN / 4 + 255) / 256, 256, 0, stream>>>(x, xb);

  // all 22 GEMMs, one dispatch, XCD-ownership block order
  gemm_mfma_kernel<<<GEMM_BLOCKS, 256, 0, stream>>>(xb, Wt, Yall);

  // ---- Clenshaw schedule (host-side bookkeeping), identical to R3/R7/R8 ----
  const int nK[4] = {4, 5, 6, 7};
  const int st[4] = {0, 4, 9, 15};
  unsigned short* S[4]; // spare panels alias xb (xb no longer needed after GEMM)
  for (int c = 0; c < 4; c++) S[c] = xb + (size_t)c * NF;

  StepA sched[5];
  int nact[5] = {0, 0, 0, 0, 0};
  FinalA fa;

  for (int c = 3; c >= 0; c--) {
    int n = nK[c] - 1;        // Clenshaw degree (props per conv)
    int s0 = 6 - n;           // first global step for this conv
    unsigned short* Yn = Yall + (size_t)(st[c] + n) * NF; // holds b_n = Y_n initially
    unsigned short* A = S[c];
    for (int p = 1; p <= n; p++) {
      int s = s0 + p - 1;
      if (p < n) {
        unsigned short* H = (p & 1) ? Yn : A;
        unsigned short* D = (p & 1) ? A : Yn;
        int j = nact[s]++;
        sched[s].H[j] = H;
        sched[s].Y[j] = Yall + (size_t)(st[c] + n - p) * NF;
        sched[s].P[j] = (p == 1) ? nullptr : D; // in-place over b_{k+2}
        sched[s].D[j] = D;
      } else { // final at s == 5
        int j = 3 - c;
        fa.H[j] = ((n - 1) & 1) ? A : Yn; // loc(b_1)
        fa.P[j] = ((n - 2) & 1) ? A : Yn; // loc(b_2)
        fa.Y[j] = Yall + (size_t)st[c] * NF;
        fa.B[j] = b[c];
        fa.conv[j] = c;
      }
    }
  }

  // pad unused slots with slot 0 (never dereferenced: template bound = nact)
  for (int s = 0; s < 5; s++)
    for (int j = nact[s]; j < 4; j++) {
      sched[s].H[j] = sched[s].H[0];
      sched[s].Y[j] = sched[s].Y[0];
      sched[s].P[j] = sched[s].P[0];
      sched[s].D[j] = sched[s].D[0];
    }

  const int grid_cl = NN / 8; // 1250 (8 nodes x 36 lanes x 2 halves per block)
  for (int s = 0; s < 5; s++) {
    switch (nact[s]) {
      case 1: cl_step_fused<1><<<grid_cl, 576, 0, stream>>>(sched[s], rowptr, srcarr, wn); break;
      case 2: cl_step_fused<2><<<grid_cl, 576, 0, stream>>>(sched[s], rowptr, srcarr, wn); break;
      case 3: cl_step_fused<3><<<grid_cl, 576, 0, stream>>>(sched[s], rowptr, srcarr, wn); break;
      default: cl_step_fused<4><<<grid_cl, 576, 0, stream>>>(sched[s], rowptr, srcarr, wn); break;
    }
  }
  cl_final_fused<<<grid_cl, 576, 0, stream>>>(fa, rowptr, srcarr, wn, out);
}